// Round 14
// baseline (118.783 us; speedup 1.0000x reference)
//
#include <hip/hip_runtime.h>

// Problem constants
#define Tn   1024
#define Bn   4
#define En   1024
#define Hn   16
#define HIDn 1024
#define SIGn 64
#define Mn   (Tn * Bn)   // 4096 rows when x viewed as (T*B, E)

typedef short  s8x8  __attribute__((ext_vector_type(8)));   // 8 bf16 (4 VGPRs)
typedef float  f32x4 __attribute__((ext_vector_type(4)));   // MFMA acc

__device__ __forceinline__ unsigned short f2bf(float f) {
    unsigned int x = __float_as_uint(f);
    unsigned int r = (x + 0x7fffu + ((x >> 16) & 1u)) >> 16;   // RNE
    return (unsigned short)r;
}
// v_exp_f32: D = 2^S0.
__device__ __forceinline__ float exp2asm(float x) {
    float r;
    asm("v_exp_f32 %0, %1" : "=v"(r) : "v"(x));
    return r;
}
// v_cvt_pk_bf16_f32: packs 2 f32 -> 2 bf16 (RNE) in one u32 (lo = src0).
__device__ __forceinline__ unsigned int cvtpk(float a, float b) {
    unsigned int r;
    asm("v_cvt_pk_bf16_f32 %0, %1, %2" : "=v"(r) : "v"(a), "v"(b));
    return r;
}

// global -> LDS direct copy, 16B/lane. LDS dest is wave-uniform base
// (HW writes base + lane*16); global src is per-lane (swizzle goes there).
__device__ __forceinline__ void gload_lds16(const void* g, void* l) {
    __builtin_amdgcn_global_load_lds(
        (const __attribute__((address_space(1))) unsigned int*)g,
        (__attribute__((address_space(3))) unsigned int*)l, 16, 0, 0);
}

__device__ __forceinline__ void cast8(const float* s, unsigned short* d) {
    const float4* p = (const float4*)s;
    float4 a = p[0], b = p[1];
    s8x8 o;
    o[0] = (short)f2bf(a.x); o[1] = (short)f2bf(a.y);
    o[2] = (short)f2bf(a.z); o[3] = (short)f2bf(a.w);
    o[4] = (short)f2bf(b.x); o[5] = (short)f2bf(b.y);
    o[6] = (short)f2bf(b.z); o[7] = (short)f2bf(b.w);
    *(s8x8*)d = o;
}

// ---------------------------------------------------------------------------
// Merged prep (R11-verbatim): weight casts + x cast + bias concat.
// ---------------------------------------------------------------------------
__global__ __launch_bounds__(256) void prep_all(
    const float* __restrict__ x,  const float* __restrict__ W1,
    const float* __restrict__ Wq, const float* __restrict__ Wk,
    const float* __restrict__ Wv, const float* __restrict__ W2,
    const float* __restrict__ b1, const float* __restrict__ bq,
    const float* __restrict__ bk, const float* __restrict__ bv,
    unsigned short* __restrict__ Wcat, unsigned short* __restrict__ W2b,
    float* __restrict__ bcat, unsigned short* __restrict__ xb, int pre)
{
    const size_t WELEM = (size_t)En * En;
    const int y = blockIdx.y, bx = blockIdx.x, tid = threadIdx.x;
    if (y < 4) {
        const float* src = (y == 0) ? W1 : (y == 1) ? Wq : (y == 2) ? Wk : Wv;
        size_t i = (size_t)bx * 256 + tid;
        cast8(src + i * 8, Wcat + y * WELEM + i * 8);
    } else if (y == 4) {
        if (bx < 32) {
            size_t i = (size_t)bx * 256 + tid;
            cast8(W2 + i * 8, W2b + i * 8);
        } else if (bx < 48) {
            int idx = (bx - 32) * 256 + tid;
            int w = idx >> 10;
            const float* s = (w == 0) ? b1 : (w == 1) ? bq : (w == 2) ? bk : bv;
            bcat[idx] = s[idx & 1023];
        }
    } else {
        if (!pre) return;
        int q = y - 5;
        size_t i = (size_t)bx * 256 + tid;
        cast8(x + q * WELEM + i * 8, xb + q * WELEM + i * 8);
    }
}

// ---------------------------------------------------------------------------
// fused_proj8 v3 — R12 skeleton (256x256, BK=64, 8 waves 2x4, 2 bufs,
// counted vmcnt(8), validated swizzle/staging) + m201-style PHASE SPLIT:
// each K-tile's 64 MFMA/wave subdivided into 4 quadrant phases of
//   {12 ds_read -> s_barrier -> setprio(1)+16 MFMA+setprio(0) -> s_barrier}
// Fast waves issue phase p+1 ds_reads while slow waves finish phase-p MFMA
// (cross-wave ds_read||MFMA overlap, bounded drift, setprio arbitration —
// m196's isolated lever, +28-41%). STG stays at tile end: the final phase
// barrier proves all waves finished reading buf[t&1] before it's re-staged.
// vmcnt audit (R12-identical): 8 loads/wave/tile, 2 tiles prefetched;
// vmcnt(8) waits exactly tile t's loads; t=15 drains with vmcnt(0).
// ---------------------------------------------------------------------------
__global__ __launch_bounds__(512) void fused_proj8(
    const unsigned short* __restrict__ Xb,
    const unsigned short* __restrict__ Wcat, const float* __restrict__ bcat,
    unsigned short* __restrict__ t1b, unsigned short* __restrict__ qb,
    unsigned short* __restrict__ kb, unsigned short* __restrict__ vb)
{
    __shared__ __align__(16) short As[2][256 * 64];   // 2 x 32 KB
    __shared__ __align__(16) short Bs[2][256 * 64];   // 2 x 32 KB

    const int tid  = threadIdx.x;
    const int w    = tid >> 6;        // 0..7
    const int lane = tid & 63;
    const int ln15 = lane & 15;
    const int kq   = lane >> 4;       // 0..3
    const int wr   = w >> 2;          // 0..1 (row half of block)
    const int wc   = w & 3;           // 0..3 (col quarter of block)
    const int bn   = blockIdx.x;      // 0..15 over N=4096
    const int bm   = blockIdx.y;      // 0..15 over M=4096
    const size_t rowA0 = (size_t)bm * 256;
    const size_t rowB0 = (size_t)bn * 256;

    // Staging constants (R12-validated): row_local = i*64 + w*8 + rl.
    const int rl = lane >> 3;              // 0..7; row&7 == rl
    const int cg = (lane & 7) ^ rl;        // swizzled SOURCE chunk
    const unsigned short* Abase = Xb   + (rowA0 + w * 8 + rl) * 1024 + cg * 8;
    const unsigned short* Bbase = Wcat + (rowB0 + w * 8 + rl) * 1024 + cg * 8;
    const int ldsW = w * 512;              // per-wave slice in an 8KB issue block

    f32x4 acc[8][4];
#pragma unroll
    for (int m = 0; m < 8; m++)
#pragma unroll
        for (int n = 0; n < 4; n++) acc[m][n] = (f32x4){0.f, 0.f, 0.f, 0.f};

    // Stage one 256x64 K-tile (A+B) into buffer buf: 8 gloads/thread.
    auto STG = [&](int buf, int k0) {
#pragma unroll
        for (int i = 0; i < 4; i++)
            gload_lds16(Abase + (size_t)i * 64 * 1024 + k0,
                        &As[buf][i * 4096 + ldsW]);
#pragma unroll
        for (int i = 0; i < 4; i++)
            gload_lds16(Bbase + (size_t)i * 64 * 1024 + k0,
                        &Bs[buf][i * 4096 + ldsW]);
    };

    STG(0, 0);     // K-tile 0
    STG(1, 64);    // K-tile 1   (16 loads in flight)

    for (int t = 0; t < 16; t++) {
        if (t < 15)
            asm volatile("s_waitcnt vmcnt(8)" ::: "memory");  // tile t landed
        else
            asm volatile("s_waitcnt vmcnt(0)" ::: "memory");  // last tile
        __builtin_amdgcn_s_barrier();        // all waves' tile-t DMA visible
        asm volatile("" ::: "memory");
        const short* lA = &As[t & 1][0];
        const short* lB = &Bs[t & 1][0];
#pragma unroll
        for (int p = 0; p < 4; p++) {        // 4 quadrant phases
            const int rh = p >> 1, ch = p & 1;
            s8x8 af[4][2], bf[2][2];
#pragma unroll
            for (int m = 0; m < 4; m++) {
                int row = wr * 128 + (rh * 4 + m) * 16 + ln15;
#pragma unroll
                for (int kk = 0; kk < 2; kk++)
                    af[m][kk] = *(const s8x8*)&lA[row * 64 +
                        (((kk * 4 + kq) ^ (row & 7)) * 8)];
            }
#pragma unroll
            for (int n = 0; n < 2; n++) {
                int row = wc * 64 + (ch * 2 + n) * 16 + ln15;
#pragma unroll
                for (int kk = 0; kk < 2; kk++)
                    bf[n][kk] = *(const s8x8*)&lB[row * 64 +
                        (((kk * 4 + kq) ^ (row & 7)) * 8)];
            }
            __builtin_amdgcn_s_barrier();    // phase-align: reads issued
            __builtin_amdgcn_s_setprio(1);
#pragma unroll
            for (int m = 0; m < 4; m++)
#pragma unroll
                for (int n = 0; n < 2; n++)
#pragma unroll
                    for (int kk = 0; kk < 2; kk++)
                        acc[rh * 4 + m][ch * 2 + n] =
                            __builtin_amdgcn_mfma_f32_16x16x32_bf16(
                                af[m][kk], bf[n][kk],
                                acc[rh * 4 + m][ch * 2 + n], 0, 0, 0);
            __builtin_amdgcn_s_setprio(0);
            __builtin_amdgcn_s_barrier();    // phase done (p=3: buffer free)
        }
        asm volatile("" ::: "memory");
        if (t + 2 < 16) STG(t & 1, (t + 2) * 64);   // refill freed buffer
    }

    // ---- epilogue (R12-identical): per-256-col-range dst/scale/relu ----
    const int which = bn >> 2;
    unsigned short* dst = (which == 0) ? t1b : (which == 1) ? qb
                        : (which == 2) ? kb : vb;
    // q: d^-0.5 * log2(e) so attention softmax can use v_exp_f32 (2^x).
    const float scale = (which == 1) ? 0.18033688011112042f : 1.0f;
    const int   relu  = (which == 0);
    const int   cbase = (bn & 3) * 256;

    float bcol[4];
#pragma unroll
    for (int n = 0; n < 4; n++)
        bcol[n] = bcat[bn * 256 + wc * 64 + n * 16 + ln15];
#pragma unroll
    for (int m = 0; m < 8; m++) {
        size_t gr0 = rowA0 + wr * 128 + m * 16 + kq * 4;
#pragma unroll
        for (int n = 0; n < 4; n++) {
            int gc = cbase + wc * 64 + n * 16 + ln15;
#pragma unroll
            for (int j = 0; j < 4; j++) {
                float vv = acc[m][n][j] + bcol[n];
                if (relu) vv = fmaxf(vv, 0.f);
                vv *= scale;
                dst[(gr0 + j) * 1024 + gc] = f2bf(vv);
            }
        }
    }
}

// ---------------------------------------------------------------------------
// Fallback fused_proj (ROUND-6 EXACT, inline fp32 cast) — only if !pre.
// ---------------------------------------------------------------------------
__global__ __launch_bounds__(256) void fused_proj_fb(
    const float* __restrict__ X,
    const unsigned short* __restrict__ Wcat, const float* __restrict__ bcat,
    unsigned short* __restrict__ t1b, unsigned short* __restrict__ qb,
    unsigned short* __restrict__ kb, unsigned short* __restrict__ vb)
{
    __shared__ __align__(16) short As[128 * 32];
    __shared__ __align__(16) short Bs[128 * 32];
    const int tid  = threadIdx.x;
    const int wave = tid >> 6;
    const int lane = tid & 63;
    const int ln15 = lane & 15;
    const int kq   = lane >> 4;
    const int wr   = wave >> 1;
    const int wc   = wave & 1;
    const int bn   = blockIdx.x;
    const int bm   = blockIdx.y;
    const size_t rowA0 = (size_t)bm * 128;
    const size_t rowB0 = (size_t)bn * 128;
    const int lrow   = lane >> 2;
    const int lchunk = lane & 3;

    f32x4 acc[4][4];
#pragma unroll
    for (int m = 0; m < 4; m++)
#pragma unroll
        for (int n = 0; n < 4; n++) acc[m][n] = (f32x4){0.f, 0.f, 0.f, 0.f};

    for (int k0 = 0; k0 < 1024; k0 += 32) {
#pragma unroll
        for (int i = 0; i < 2; i++) {
            int row = wave * 32 + i * 16 + lrow;
            int c   = lchunk ^ ((row >> 1) & 3);
            gload_lds16(Wcat + (rowB0 + row) * 1024 + k0 + c * 8,
                        &Bs[(wave * 32 + i * 16) * 32]);
        }
        {
            const int srow = tid >> 1;
            const int scol = (tid & 1) * 16;
            const float4* src = (const float4*)(X + (rowA0 + srow) * 1024 + k0 + scol);
            float4 a = src[0], b = src[1], c4 = src[2], d4 = src[3];
            s8x8 v0, v1;
            v0[0] = (short)f2bf(a.x);  v0[1] = (short)f2bf(a.y);
            v0[2] = (short)f2bf(a.z);  v0[3] = (short)f2bf(a.w);
            v0[4] = (short)f2bf(b.x);  v0[5] = (short)f2bf(b.y);
            v0[6] = (short)f2bf(b.z);  v0[7] = (short)f2bf(b.w);
            v1[0] = (short)f2bf(c4.x); v1[1] = (short)f2bf(c4.y);
            v1[2] = (short)f2bf(c4.z); v1[3] = (short)f2bf(c4.w);
            v1[4] = (short)f2bf(d4.x); v1[5] = (short)f2bf(d4.y);
            v1[6] = (short)f2bf(d4.z); v1[7] = (short)f2bf(d4.w);
            int sw = (srow >> 1) & 3;
            int c0 = (scol >> 3) ^ sw;
            int c1 = ((scol >> 3) + 1) ^ sw;
            *(s8x8*)&As[srow * 32 + c0 * 8] = v0;
            *(s8x8*)&As[srow * 32 + c1 * 8] = v1;
        }
        asm volatile("s_waitcnt vmcnt(0)" ::: "memory");
        __syncthreads();

        s8x8 af[4], bf[4];
#pragma unroll
        for (int m = 0; m < 4; m++) {
            int row = wr * 64 + m * 16 + ln15;
            af[m] = *(const s8x8*)&As[row * 32 + (kq ^ ((row >> 1) & 3)) * 8];
        }
#pragma unroll
        for (int n = 0; n < 4; n++) {
            int row = wc * 64 + n * 16 + ln15;
            bf[n] = *(const s8x8*)&Bs[row * 32 + (kq ^ ((row >> 1) & 3)) * 8];
        }
#pragma unroll
        for (int m = 0; m < 4; m++)
#pragma unroll
            for (int n = 0; n < 4; n++)
                acc[m][n] = __builtin_amdgcn_mfma_f32_16x16x32_bf16(
                    af[m], bf[n], acc[m][n], 0, 0, 0);
        __syncthreads();
    }

    const int which = bn >> 3;
    unsigned short* dst = (which == 0) ? t1b : (which == 1) ? qb
                        : (which == 2) ? kb : vb;
    const float scale = (which == 1) ? 0.18033688011112042f : 1.0f;
    const int   relu  = (which == 0);
    const int   cbase = (bn & 7) * 128;

    float bcol[4];
#pragma unroll
    for (int n = 0; n < 4; n++)
        bcol[n] = bcat[bn * 128 + wc * 64 + n * 16 + ln15];
#pragma unroll
    for (int m = 0; m < 4; m++) {
        size_t gr0 = rowA0 + wr * 64 + m * 16 + kq * 4;
#pragma unroll
        for (int n = 0; n < 4; n++) {
            int gc = cbase + wc * 64 + n * 16 + ln15;
#pragma unroll
            for (int j = 0; j < 4; j++) {
                float vv = acc[m][n][j] + bcol[n];
                if (relu) vv = fmaxf(vv, 0.f);
                vv *= scale;
                dst[(gr0 + j) * 1024 + gc] = f2bf(vv);
            }
        }
    }
}

// ---------------------------------------------------------------------------
// Output projection (ROUND-6 EXACT, passing).
// ---------------------------------------------------------------------------
__global__ __launch_bounds__(256) void out_proj(
    const unsigned short* __restrict__ A, const unsigned short* __restrict__ W,
    const float* __restrict__ bias, float* __restrict__ C)
{
    __shared__ __align__(16) short As[64 * 32];
    __shared__ __align__(16) short Bs[128 * 32];
    const int tid  = threadIdx.x;
    const int wave = tid >> 6;
    const int lane = tid & 63;
    const int ln15 = lane & 15;
    const int kq   = lane >> 4;
    const int wr   = wave >> 1;
    const int wc   = wave & 1;
    const size_t rowA0 = (size_t)blockIdx.y * 64;
    const size_t rowB0 = (size_t)blockIdx.x * 128;
    const int lrow   = lane >> 2;
    const int lchunk = lane & 3;

    f32x4 acc[2][4];
#pragma unroll
    for (int m = 0; m < 2; m++)
#pragma unroll
        for (int n = 0; n < 4; n++) acc[m][n] = (f32x4){0.f, 0.f, 0.f, 0.f};

    for (int k0 = 0; k0 < 1024; k0 += 32) {
        {
            int row = wave * 16 + lrow;
            int c   = lchunk ^ ((row >> 1) & 3);
            gload_lds16(A + (rowA0 + row) * 1024 + k0 + c * 8,
                        &As[(wave * 16) * 32]);
        }
#pragma unroll
        for (int i = 0; i < 2; i++) {
            int row = wave * 32 + i * 16 + lrow;
            int c   = lchunk ^ ((row >> 1) & 3);
            gload_lds16(W + (rowB0 + row) * 1024 + k0 + c * 8,
                        &Bs[(wave * 32 + i * 16) * 32]);
        }
        asm volatile("s_waitcnt vmcnt(0)" ::: "memory");
        __syncthreads();

        s8x8 af[2], bf[4];
#pragma unroll
        for (int m = 0; m < 2; m++) {
            int row = wr * 32 + m * 16 + ln15;
            af[m] = *(const s8x8*)&As[row * 32 + (kq ^ ((row >> 1) & 3)) * 8];
        }
#pragma unroll
        for (int n = 0; n < 4; n++) {
            int row = wc * 64 + n * 16 + ln15;
            bf[n] = *(const s8x8*)&Bs[row * 32 + (kq ^ ((row >> 1) & 3)) * 8];
        }
#pragma unroll
        for (int m = 0; m < 2; m++)
#pragma unroll
            for (int n = 0; n < 4; n++)
                acc[m][n] = __builtin_amdgcn_mfma_f32_16x16x32_bf16(
                    af[m], bf[n], acc[m][n], 0, 0, 0);
        __syncthreads();
    }

    float bcol[4];
#pragma unroll
    for (int n = 0; n < 4; n++)
        bcol[n] = bias[rowB0 + wc * 64 + n * 16 + ln15];
#pragma unroll
    for (int m = 0; m < 2; m++) {
        size_t gr0 = rowA0 + wr * 32 + m * 16 + kq * 4;
#pragma unroll
        for (int n = 0; n < 4; n++) {
            size_t gc = rowB0 + wc * 64 + n * 16 + ln15;
#pragma unroll
            for (int j = 0; j < 4; j++)
                C[(gr0 + j) * 1024 + gc] = acc[m][n][j] + bcol[n];
        }
    }
}

// ---------------------------------------------------------------------------
// t2gate body (R11-verbatim).
// ---------------------------------------------------------------------------
__device__ __forceinline__ void t2gate_body(
    int blk, int tid,
    const unsigned short* __restrict__ t1, const unsigned short* __restrict__ W2b,
    const float* __restrict__ b2, const float* __restrict__ hs,
    float* __restrict__ gate,
    short* As, short* Bs, float (*t2s)[65], float (*hss)[65])
{
    const int wave  = tid >> 6;
    const int lane  = tid & 63;
    const int ln15  = lane & 15;
    const int kq    = lane >> 4;
    const int lrow8 = lane >> 3;
    const int lch   = lane & 7;
    const int m0    = blk * 16;

    {
        int r = tid >> 4, c = (tid & 15) * 4;
        float4 v = *(const float4*)(hs + r * 64 + c);
        hss[r][c] = v.x; hss[r][c + 1] = v.y; hss[r][c + 2] = v.z; hss[r][c + 3] = v.w;
    }

    f32x4 acc = (f32x4){0.f, 0.f, 0.f, 0.f};
    for (int k0 = 0; k0 < 1024; k0 += 64) {
        if (wave < 2) {
            int row = wave * 8 + lrow8;
            int cg  = lch ^ (row & 7);
            gload_lds16(t1 + (size_t)(m0 + row) * 1024 + k0 + cg * 8,
                        As + (wave * 8) * 64);
        }
#pragma unroll
        for (int i = 0; i < 2; i++) {
            int row = wave * 16 + i * 8 + lrow8;
            int cg  = lch ^ (row & 7);
            gload_lds16(W2b + (size_t)row * 1024 + k0 + cg * 8,
                        Bs + (wave * 16 + i * 8) * 64);
        }
        asm volatile("s_waitcnt vmcnt(0)" ::: "memory");
        __syncthreads();

#pragma unroll
        for (int kk = 0; kk < 2; kk++) {
            int arow = ln15;
            int brow = wave * 16 + ln15;
            s8x8 af = *(const s8x8*)(As + arow * 64 + (((kk * 4 + kq) ^ (arow & 7)) * 8));
            s8x8 bf = *(const s8x8*)(Bs + brow * 64 + (((kk * 4 + kq) ^ (brow & 7)) * 8));
            acc = __builtin_amdgcn_mfma_f32_16x16x32_bf16(af, bf, acc, 0, 0, 0);
        }
        __syncthreads();
    }

#pragma unroll
    for (int j = 0; j < 4; j++)
        t2s[kq * 4 + j][wave * 16 + ln15] = acc[j] + b2[wave * 16 + ln15];
    __syncthreads();

    int r = tid >> 4, hd = tid & 15;
    float s = 0.f;
#pragma unroll 16
    for (int d = 0; d < 64; d++) s += t2s[r][d] * hss[hd][d];
    float mx = s;
    mx = fmaxf(mx, __shfl_xor(mx, 1));
    mx = fmaxf(mx, __shfl_xor(mx, 2));
    mx = fmaxf(mx, __shfl_xor(mx, 4));
    mx = fmaxf(mx, __shfl_xor(mx, 8));
    float e = __expf(s - mx);
    float sum = e;
    sum += __shfl_xor(sum, 1);
    sum += __shfl_xor(sum, 2);
    sum += __shfl_xor(sum, 4);
    sum += __shfl_xor(sum, 8);
    gate[(size_t)(m0 + r) * Hn + hd] = e / sum;
}

__device__ __forceinline__ void vtrans_body(
    int bh, int t0, int tid,
    const unsigned short* __restrict__ vb, unsigned short* __restrict__ vt,
    unsigned short (*ts)[65])
{
    const int b = bh >> 4, h = bh & 15;
    {
        int tr = tid >> 2, dq = (tid & 3) * 16;
        const unsigned short* src =
            vb + ((size_t)(t0 + tr) * Bn + b) * En + h * 64 + dq;
        s8x8 a = *(const s8x8*)src;
        s8x8 c = *(const s8x8*)(src + 8);
#pragma unroll
        for (int i = 0; i < 8; i++) {
            ts[tr][dq + i]     = (unsigned short)a[i];
            ts[tr][dq + 8 + i] = (unsigned short)c[i];
        }
    }
    __syncthreads();
    {
        int dr = tid >> 2, tq = (tid & 3) * 16;
        unsigned short* dst = vt + ((size_t)bh * 64 + dr) * Tn + t0 + tq;
        s8x8 o0, o1;
#pragma unroll
        for (int i = 0; i < 8; i++) {
            o0[i] = (short)ts[tq + i][dr];
            o1[i] = (short)ts[tq + 8 + i][dr];
        }
        *(s8x8*)dst = o0;
        *(s8x8*)(dst + 8) = o1;
    }
}

// Standalone kernels (!pre path).
__global__ __launch_bounds__(256) void t2gate_k(
    const unsigned short* __restrict__ t1, const unsigned short* __restrict__ W2b,
    const float* __restrict__ b2, const float* __restrict__ hs,
    float* __restrict__ gate)
{
    __shared__ __align__(16) short As[16 * 64];
    __shared__ __align__(16) short Bs[64 * 64];
    __shared__ float t2s[16][65];
    __shared__ float hss[16][65];
    t2gate_body(blockIdx.x, threadIdx.x, t1, W2b, b2, hs, gate, As, Bs, t2s, hss);
}
__global__ __launch_bounds__(256) void trans_wo_k(
    const unsigned short* __restrict__ vb, unsigned short* __restrict__ vt,
    const float* __restrict__ Wo, unsigned short* __restrict__ Wob)
{
    const int bx = blockIdx.x, tid = threadIdx.x;
    if (bx >= 1024) {
        size_t i = (size_t)(bx - 1024) * 256 + tid;
        cast8(Wo + i * 8, Wob + i * 8);
        return;
    }
    __shared__ unsigned short ts[64][65];
    vtrans_body(bx & 63, (bx >> 6) * 64, tid, vb, vt, ts);
}

// Merged mid-stage (pre path, validated R10-R13).
__global__ __launch_bounds__(256) void midstage(
    const unsigned short* __restrict__ t1, const unsigned short* __restrict__ W2b,
    const float* __restrict__ b2, const float* __restrict__ hs,
    float* __restrict__ gate,
    const unsigned short* __restrict__ vb, unsigned short* __restrict__ vt,
    const float* __restrict__ Wo, unsigned short* __restrict__ Wob)
{
    __shared__ __align__(16) short As[16 * 64];
    __shared__ __align__(16) short Bs[64 * 64];
    __shared__ float t2s[16][65];
    __shared__ float hss[16][65];
    __shared__ unsigned short ts[64][65];
    const int bx = blockIdx.x, tid = threadIdx.x;
    if (bx < 256) {
        t2gate_body(bx, tid, t1, W2b, b2, hs, gate, As, Bs, t2s, hss);
    } else if (bx < 1280) {
        int v = bx - 256;
        vtrans_body(v & 63, (v >> 6) * 64, tid, vb, vt, ts);
    } else {
        size_t i = (size_t)(bx - 1280) * 256 + tid;
        cast8(Wo + i * 8, Wob + i * 8);
    }
}

// ---------------------------------------------------------------------------
// MFMA flash attention (R9 8-wave version, passing, unchanged).
// ---------------------------------------------------------------------------
__global__ __launch_bounds__(512, 2) void attn_mfma(
    const unsigned short* __restrict__ q, const unsigned short* __restrict__ k,
    const unsigned short* __restrict__ vt, const float* __restrict__ gate,
    unsigned short* __restrict__ o)
{
    __shared__ __align__(16) short Kls[2][64 * 64];
    __shared__ __align__(16) short Vls[2][64 * 64];

    const int tid  = threadIdx.x;
    const int w    = tid >> 6;
    const int lane = tid & 63;
    const int ln   = lane & 15;
    const int kq   = lane >> 4;
    const int bh   = blockIdx.x;
    const int b    = bh >> 4;
    const int h    = bh & 15;
    const int qt   = blockIdx.y;

    s8x8 qf[2];
    {
        const int qrow = qt * 128 + w * 16 + ln;
        const unsigned short* src =
            q + ((size_t)qrow * Bn + b) * En + h * 64 + kq * 8;
        qf[0] = *(const s8x8*)(src);
        qf[1] = *(const s8x8*)(src + 32);
    }

    f32x4 OT[4];
#pragma unroll
    for (int n = 0; n < 4; n++) OT[n] = (f32x4){0.f, 0.f, 0.f, 0.f};
    float mrun = -1e30f, lrun = 0.f;

    const int srow = w * 8 + (lane >> 3);
    const int sch  = (lane & 7) ^ (srow & 7);
    const int sn  = srow >> 4;
    const int sK0 = 32 * (sn >> 1) + 4 * (sn & 1)
                  + 8 * ((srow >> 2) & 3) + (srow & 3);

    auto stage = [&](int bufi, int s0) {
        const unsigned short* gk =
            k + ((size_t)(s0 + sK0) * Bn + b) * En + h * 64 + sch * 8;
        gload_lds16(gk, &Kls[bufi][w * 512]);
        const unsigned short* gv =
            vt + ((size_t)bh * 64 + srow) * Tn + s0 + sch * 8;
        gload_lds16(gv, &Vls[bufi][w * 512]);
    };

    stage(0, 0);
    asm volatile("s_waitcnt vmcnt(0)" ::: "memory");
    __syncthreads();

    int cur = 0;
    for (int t = 0; t < Tn / 64; t++) {
        if (t + 1 < Tn / 64) stage(cur ^ 1, (t + 1) * 64);

        f32x4 S[4];
        __builtin_amdgcn_s_setprio(1);
#pragma unroll
        for (int n = 0; n < 4; n++) {
            S[n] = (f32x4){0.f, 0.f, 0.f, 0.f};
#pragma unroll
            for (int kk = 0; kk < 2; kk++) {
                int row = n * 16 + ln;
                int cc  = (kk * 4 + kq) ^ (row & 7);
                s8x8 kf = *(const s8x8*)&Kls[cur][row * 64 + cc * 8];
                S[n] = __builtin_amdgcn_mfma_f32_16x16x32_bf16(kf, qf[kk], S[n], 0, 0, 0);
            }
        }
        __builtin_amdgcn_s_setprio(0);

        float rm;
        {
            f32x4 t0 = S[0];
#pragma unroll
            for (int n = 1; n < 4; n++) {
                t0[0] = fmaxf(t0[0], S[n][0]); t0[1] = fmaxf(t0[1], S[n][1]);
                t0[2] = fmaxf(t0[2], S[n][2]); t0[3] = fmaxf(t0[3], S[n][3]);
            }
            rm = fmaxf(fmaxf(t0[0], t0[1]), fmaxf(t0[2], t0[3]));
            rm = fmaxf(rm, __shfl_xor(rm, 16));
            rm = fmaxf(rm, __shfl_xor(rm, 32));
        }

        if (__any(rm > mrun + 8.0f)) {
            float mnew = fmaxf(mrun, rm);
            float fs = exp2asm(mrun - mnew);
            lrun *= fs;
#pragma unroll
            for (int n = 0; n < 4; n++) {
                OT[n][0] *= fs; OT[n][1] *= fs; OT[n][2] *= fs; OT[n][3] *= fs;
            }
            mrun = mnew;
        }

        float ps = 0.f;
#pragma unroll
        for (int n = 0; n < 4; n++) {
            S[n][0] = exp2asm(S[n][0] - mrun); ps += S[n][0];
            S[n][1] = exp2asm(S[n][1] - mrun); ps += S[n][1];
            S[n][2] = exp2asm(S[n][2] - mrun); ps += S[n][2];
            S[n][3] = exp2asm(S[n][3] - mrun); ps += S[n][3];
        }
        ps += __shfl_xor(ps, 16);
        ps += __shfl_xor(ps, 32);
        lrun += ps;

        union { unsigned int u[4]; s8x8 v; } pb[2];
#pragma unroll
        for (int kk = 0; kk < 2; kk++) {
            pb[kk].u[0] = cvtpk(S[2 * kk][0],     S[2 * kk][1]);
            pb[kk].u[1] = cvtpk(S[2 * kk][2],     S[2 * kk][3]);
            pb[kk].u[2] = cvtpk(S[2 * kk + 1][0], S[2 * kk + 1][1]);
            pb[kk].u[3] = cvtpk(S[2 * kk + 1][2], S[2 * kk + 1][3]);
        }

        __builtin_amdgcn_s_setprio(1);
#pragma unroll
        for (int kk = 0; kk < 2; kk++) {
#pragma unroll
            for (int n = 0; n < 4; n++) {
                int row = n * 16 + ln;
                int cv  = (kk * 4 + kq) ^ (row & 7);
                s8x8 vf = *(const s8x8*)&Vls[cur][row * 64 + cv * 8];
                OT[n] = __builtin_amdgcn_mfma_f32_16x16x32_bf16(vf, pb[kk].v, OT[n], 0, 0, 0);
            }
        }
        __builtin_amdgcn_s_setprio(0);

        asm volatile("s_waitcnt vmcnt(0)" ::: "memory");
        __syncthreads();
        cur ^= 1;
    }

    {
        int tq = qt * 128 + w * 16 + ln;
        size_t m = (size_t)tq * Bn + b;
        float g = gate[m * Hn + h] / lrun;
        unsigned short* dst = o + m * En + h * 64;
#pragma unroll
        for (int n = 0; n < 4; n++) {
            int d0 = n * 16 + kq * 4;
            uint2 pkv;
            pkv.x = cvtpk(OT[n][0] * g, OT[n][1] * g);
            pkv.y = cvtpk(OT[n][2] * g, OT[n][3] * g);
            *(uint2*)(dst + d0) = pkv;
        }
    }
}

// ---------------------------------------------------------------------------
// Workspace layout (unchanged from R11-R13).
// pre path (5 dispatches): prep_all, fused_proj8, midstage, attn_mfma,
//   out_proj.  Aliases: vtb <- xb (dead after fused_proj8), Wob <- Wcat
//   (dead after fused_proj8), ob <- vb (dead after V transpose).
// ---------------------------------------------------------------------------
extern "C" void kernel_launch(void* const* d_in, const int* in_sizes, int n_in,
                              void* d_out, int out_size, void* d_ws, size_t ws_size,
                              hipStream_t stream)
{
    const float* x  = (const float*)d_in[0];
    const float* Wq = (const float*)d_in[1];
    const float* bq = (const float*)d_in[2];
    const float* Wk = (const float*)d_in[3];
    const float* bk = (const float*)d_in[4];
    const float* Wv = (const float*)d_in[5];
    const float* bv = (const float*)d_in[6];
    const float* Wo = (const float*)d_in[7];
    const float* bo = (const float*)d_in[8];
    const float* W1 = (const float*)d_in[9];
    const float* b1 = (const float*)d_in[10];
    const float* W2 = (const float*)d_in[11];
    const float* b2 = (const float*)d_in[12];
    const float* hs = (const float*)d_in[13];

    const size_t WELEM = (size_t)En * En;
    unsigned short* Wcat = (unsigned short*)d_ws;            // 4*WELEM
    unsigned short* W2b  = Wcat + 4 * WELEM;                 // 64*1024
    float* bcat = (float*)(W2b + (size_t)SIGn * HIDn);       // 4096 floats
    float* gate = bcat + 4096;                               // 4096*16 floats
    unsigned short* t1b = (unsigned short*)(gate + (size_t)Mn * Hn);
    unsigned short* qb  = t1b + (size_t)Mn * En;
    unsigned short* kb  = qb  + (size_t)Mn * En;
    unsigned short* vb  = kb  + (size_t)Mn * En;
    unsigned short* xb  = vb  + (size_t)Mn * En;             // optional +8MB
    unsigned short* Wob = Wcat;   // alias
    unsigned short* ob  = vb;     // alias

    const size_t need_xb =
        (size_t)((char*)(xb + (size_t)Mn * En) - (char*)d_ws);
    const bool pre = ws_size >= need_xb;   // deterministic

    dim3 blk(256);

    prep_all<<<dim3(512, 9), blk, 0, stream>>>(
        x, W1, Wq, Wk, Wv, W2, b1, bq, bk, bv, Wcat, W2b, bcat, xb, (int)pre);

    if (pre) {
        unsigned short* vtb = xb;    // xb dead after fused_proj8
        fused_proj8<<<dim3(16, 16), dim3(512), 0, stream>>>(
            xb, Wcat, bcat, t1b, qb, kb, vb);
        midstage<<<dim3(1792), blk, 0, stream>>>(
            t1b, W2b, b2, hs, gate, vb, vtb, Wo, Wob);
        attn_mfma<<<dim3(Bn * Hn, Tn / 128), dim3(512), 0, stream>>>(
            qb, kb, vtb, gate, ob);
    } else {
        unsigned short* vtb = t1b;   // t1b dead after t2gate (sequential)
        fused_proj_fb<<<dim3(32, 32), blk, 0, stream>>>(
            x, Wcat, bcat, t1b, qb, kb, vb);
        t2gate_k<<<dim3(Mn / 16), blk, 0, stream>>>(t1b, W2b, b2, hs, gate);
        trans_wo_k<<<dim3(1536), blk, 0, stream>>>(vb, vtb, Wo, Wob);
        attn_mfma<<<dim3(Bn * Hn, Tn / 128), dim3(512), 0, stream>>>(
            qb, kb, vtb, gate, ob);
    }

    out_proj<<<dim3(En / 128, Mn / 64), blk, 0, stream>>>(ob, Wob, bo, (float*)d_out);
}

// Round 15
// 112.992 us; speedup vs baseline: 1.0513x; 1.0513x over previous
//
#include <hip/hip_runtime.h>

// Problem constants
#define Tn   1024
#define Bn   4
#define En   1024
#define Hn   16
#define HIDn 1024
#define SIGn 64
#define Mn   (Tn * Bn)   // 4096 rows when x viewed as (T*B, E)

typedef short  s8x8  __attribute__((ext_vector_type(8)));   // 8 bf16 (4 VGPRs)
typedef float  f32x4 __attribute__((ext_vector_type(4)));   // MFMA acc

__device__ __forceinline__ unsigned short f2bf(float f) {
    unsigned int x = __float_as_uint(f);
    unsigned int r = (x + 0x7fffu + ((x >> 16) & 1u)) >> 16;   // RNE
    return (unsigned short)r;
}
// v_exp_f32: D = 2^S0.
__device__ __forceinline__ float exp2asm(float x) {
    float r;
    asm("v_exp_f32 %0, %1" : "=v"(r) : "v"(x));
    return r;
}
// v_cvt_pk_bf16_f32: packs 2 f32 -> 2 bf16 (RNE) in one u32 (lo = src0).
__device__ __forceinline__ unsigned int cvtpk(float a, float b) {
    unsigned int r;
    asm("v_cvt_pk_bf16_f32 %0, %1, %2" : "=v"(r) : "v"(a), "v"(b));
    return r;
}

// global -> LDS direct copy, 16B/lane. LDS dest is wave-uniform base
// (HW writes base + lane*16); global src is per-lane (swizzle goes there).
__device__ __forceinline__ void gload_lds16(const void* g, void* l) {
    __builtin_amdgcn_global_load_lds(
        (const __attribute__((address_space(1))) unsigned int*)g,
        (__attribute__((address_space(3))) unsigned int*)l, 16, 0, 0);
}

__device__ __forceinline__ void cast8(const float* s, unsigned short* d) {
    const float4* p = (const float4*)s;
    float4 a = p[0], b = p[1];
    s8x8 o;
    o[0] = (short)f2bf(a.x); o[1] = (short)f2bf(a.y);
    o[2] = (short)f2bf(a.z); o[3] = (short)f2bf(a.w);
    o[4] = (short)f2bf(b.x); o[5] = (short)f2bf(b.y);
    o[6] = (short)f2bf(b.z); o[7] = (short)f2bf(b.w);
    *(s8x8*)d = o;
}

// ---------------------------------------------------------------------------
// Merged prep (R11-verbatim): weight casts + x cast + bias concat.
// ---------------------------------------------------------------------------
__global__ __launch_bounds__(256) void prep_all(
    const float* __restrict__ x,  const float* __restrict__ W1,
    const float* __restrict__ Wq, const float* __restrict__ Wk,
    const float* __restrict__ Wv, const float* __restrict__ W2,
    const float* __restrict__ b1, const float* __restrict__ bq,
    const float* __restrict__ bk, const float* __restrict__ bv,
    unsigned short* __restrict__ Wcat, unsigned short* __restrict__ W2b,
    float* __restrict__ bcat, unsigned short* __restrict__ xb, int pre)
{
    const size_t WELEM = (size_t)En * En;
    const int y = blockIdx.y, bx = blockIdx.x, tid = threadIdx.x;
    if (y < 4) {
        const float* src = (y == 0) ? W1 : (y == 1) ? Wq : (y == 2) ? Wk : Wv;
        size_t i = (size_t)bx * 256 + tid;
        cast8(src + i * 8, Wcat + y * WELEM + i * 8);
    } else if (y == 4) {
        if (bx < 32) {
            size_t i = (size_t)bx * 256 + tid;
            cast8(W2 + i * 8, W2b + i * 8);
        } else if (bx < 48) {
            int idx = (bx - 32) * 256 + tid;
            int w = idx >> 10;
            const float* s = (w == 0) ? b1 : (w == 1) ? bq : (w == 2) ? bk : bv;
            bcat[idx] = s[idx & 1023];
        }
    } else {
        if (!pre) return;
        int q = y - 5;
        size_t i = (size_t)bx * 256 + tid;
        cast8(x + q * WELEM + i * 8, xb + q * WELEM + i * 8);
    }
}

// ---------------------------------------------------------------------------
// fused_proj8 — R12 v1 EXACT (best measured of 6 variants: 46.2us).
// 256x256 tile, BK=64, 8 waves (2x4), 2 bufs, counted-vmcnt deep pipeline
// with RAW s_barrier. A/B evidence: v1 monolithic = 46.2us; v2 (3-buf,
// BK=32, hoisted frags) = 49.4; v3 (phase-split barriers) = 52.4 — m196's
// "coarse split without per-phase interleave hurts" confirmed in-session.
// Sync per K-tile t: own vmcnt(8) (tile t's 8 loads oldest; t+1 in flight;
// never drain 0 mid-loop) -> s_barrier (all waves' tile-t DMA visible) ->
// 4 quadrant compute (compiler emits lgkmcnt for ds_read->MFMA) ->
// s_barrier (all reads retired) -> STG(t+2) into freed buffer.
// ---------------------------------------------------------------------------
__global__ __launch_bounds__(512) void fused_proj8(
    const unsigned short* __restrict__ Xb,
    const unsigned short* __restrict__ Wcat, const float* __restrict__ bcat,
    unsigned short* __restrict__ t1b, unsigned short* __restrict__ qb,
    unsigned short* __restrict__ kb, unsigned short* __restrict__ vb)
{
    __shared__ __align__(16) short As[2][256 * 64];   // 2 x 32 KB
    __shared__ __align__(16) short Bs[2][256 * 64];   // 2 x 32 KB

    const int tid  = threadIdx.x;
    const int w    = tid >> 6;        // 0..7
    const int lane = tid & 63;
    const int ln15 = lane & 15;
    const int kq   = lane >> 4;       // 0..3
    const int wr   = w >> 2;          // 0..1 (row half of block)
    const int wc   = w & 3;           // 0..3 (col quarter of block)
    const int bn   = blockIdx.x;      // 0..15 over N=4096
    const int bm   = blockIdx.y;      // 0..15 over M=4096
    const size_t rowA0 = (size_t)bm * 256;
    const size_t rowB0 = (size_t)bn * 256;

    // Staging constants (per thread): row_local = i*64 + w*8 + rl.
    const int rl = lane >> 3;              // 0..7; row&7 == rl
    const int cg = (lane & 7) ^ rl;        // swizzled SOURCE chunk
    const unsigned short* Abase = Xb   + (rowA0 + w * 8 + rl) * 1024 + cg * 8;
    const unsigned short* Bbase = Wcat + (rowB0 + w * 8 + rl) * 1024 + cg * 8;
    const int ldsW = w * 512;              // per-wave slice in an 8KB issue block

    f32x4 acc[8][4];
#pragma unroll
    for (int m = 0; m < 8; m++)
#pragma unroll
        for (int n = 0; n < 4; n++) acc[m][n] = (f32x4){0.f, 0.f, 0.f, 0.f};

    // Stage one 256x64 K-tile (A+B) into buffer buf: 8 gloads/thread.
    auto STG = [&](int buf, int k0) {
#pragma unroll
        for (int i = 0; i < 4; i++)
            gload_lds16(Abase + (size_t)i * 64 * 1024 + k0,
                        &As[buf][i * 4096 + ldsW]);
#pragma unroll
        for (int i = 0; i < 4; i++)
            gload_lds16(Bbase + (size_t)i * 64 * 1024 + k0,
                        &Bs[buf][i * 4096 + ldsW]);
    };

    // Compute this wave's 64 MFMA for one K-tile, 4 quadrant phases.
    auto COMPUTE = [&](const short* lA, const short* lB) {
#pragma unroll
        for (int q = 0; q < 4; q++) {
            const int rh = q >> 1, ch = q & 1;
            s8x8 af[4][2], bf[2][2];
#pragma unroll
            for (int m = 0; m < 2 + 2; m++) {
                int row = wr * 128 + (rh * 4 + m) * 16 + ln15;
#pragma unroll
                for (int kk = 0; kk < 2; kk++)
                    af[m][kk] = *(const s8x8*)&lA[row * 64 +
                        (((kk * 4 + kq) ^ (row & 7)) * 8)];
            }
#pragma unroll
            for (int n = 0; n < 2; n++) {
                int row = wc * 64 + (ch * 2 + n) * 16 + ln15;
#pragma unroll
                for (int kk = 0; kk < 2; kk++)
                    bf[n][kk] = *(const s8x8*)&lB[row * 64 +
                        (((kk * 4 + kq) ^ (row & 7)) * 8)];
            }
            __builtin_amdgcn_s_setprio(1);
#pragma unroll
            for (int m = 0; m < 4; m++)
#pragma unroll
                for (int n = 0; n < 2; n++)
#pragma unroll
                    for (int kk = 0; kk < 2; kk++)
                        acc[rh * 4 + m][ch * 2 + n] =
                            __builtin_amdgcn_mfma_f32_16x16x32_bf16(
                                af[m][kk], bf[n][kk],
                                acc[rh * 4 + m][ch * 2 + n], 0, 0, 0);
            __builtin_amdgcn_s_setprio(0);
        }
    };

    STG(0, 0);     // K-tile 0
    STG(1, 64);    // K-tile 1   (16 loads in flight)

    for (int t = 0; t < 16; t++) {
        if (t < 15)
            asm volatile("s_waitcnt vmcnt(8)" ::: "memory");  // tile t landed
        else
            asm volatile("s_waitcnt vmcnt(0)" ::: "memory");  // last tile
        __builtin_amdgcn_s_barrier();        // all waves' tile-t DMA visible
        asm volatile("" ::: "memory");       // pin LDS reads below barrier
        COMPUTE(&As[t & 1][0], &Bs[t & 1][0]);
        asm volatile("" ::: "memory");       // pin reads above next barrier
        __builtin_amdgcn_s_barrier();        // all waves done reading buffer
        if (t + 2 < 16) STG(t & 1, (t + 2) * 64);   // refill freed buffer
    }

    // ---- epilogue: per-256-col-range dst/scale/relu ----
    const int which = bn >> 2;
    unsigned short* dst = (which == 0) ? t1b : (which == 1) ? qb
                        : (which == 2) ? kb : vb;
    // q: d^-0.5 * log2(e) so attention softmax can use v_exp_f32 (2^x).
    const float scale = (which == 1) ? 0.18033688011112042f : 1.0f;
    const int   relu  = (which == 0);
    const int   cbase = (bn & 3) * 256;

    float bcol[4];
#pragma unroll
    for (int n = 0; n < 4; n++)
        bcol[n] = bcat[bn * 256 + wc * 64 + n * 16 + ln15];
#pragma unroll
    for (int m = 0; m < 8; m++) {
        size_t gr0 = rowA0 + wr * 128 + m * 16 + kq * 4;
#pragma unroll
        for (int n = 0; n < 4; n++) {
            int gc = cbase + wc * 64 + n * 16 + ln15;
#pragma unroll
            for (int j = 0; j < 4; j++) {
                float vv = acc[m][n][j] + bcol[n];
                if (relu) vv = fmaxf(vv, 0.f);
                vv *= scale;
                dst[(gr0 + j) * 1024 + gc] = f2bf(vv);
            }
        }
    }
}

// ---------------------------------------------------------------------------
// Fallback fused_proj (ROUND-6 EXACT, inline fp32 cast) — only if !pre.
// ---------------------------------------------------------------------------
__global__ __launch_bounds__(256) void fused_proj_fb(
    const float* __restrict__ X,
    const unsigned short* __restrict__ Wcat, const float* __restrict__ bcat,
    unsigned short* __restrict__ t1b, unsigned short* __restrict__ qb,
    unsigned short* __restrict__ kb, unsigned short* __restrict__ vb)
{
    __shared__ __align__(16) short As[128 * 32];
    __shared__ __align__(16) short Bs[128 * 32];
    const int tid  = threadIdx.x;
    const int wave = tid >> 6;
    const int lane = tid & 63;
    const int ln15 = lane & 15;
    const int kq   = lane >> 4;
    const int wr   = wave >> 1;
    const int wc   = wave & 1;
    const int bn   = blockIdx.x;
    const int bm   = blockIdx.y;
    const size_t rowA0 = (size_t)bm * 128;
    const size_t rowB0 = (size_t)bn * 128;
    const int lrow   = lane >> 2;
    const int lchunk = lane & 3;

    f32x4 acc[4][4];
#pragma unroll
    for (int m = 0; m < 4; m++)
#pragma unroll
        for (int n = 0; n < 4; n++) acc[m][n] = (f32x4){0.f, 0.f, 0.f, 0.f};

    for (int k0 = 0; k0 < 1024; k0 += 32) {
#pragma unroll
        for (int i = 0; i < 2; i++) {
            int row = wave * 32 + i * 16 + lrow;
            int c   = lchunk ^ ((row >> 1) & 3);
            gload_lds16(Wcat + (rowB0 + row) * 1024 + k0 + c * 8,
                        &Bs[(wave * 32 + i * 16) * 32]);
        }
        {
            const int srow = tid >> 1;
            const int scol = (tid & 1) * 16;
            const float4* src = (const float4*)(X + (rowA0 + srow) * 1024 + k0 + scol);
            float4 a = src[0], b = src[1], c4 = src[2], d4 = src[3];
            s8x8 v0, v1;
            v0[0] = (short)f2bf(a.x);  v0[1] = (short)f2bf(a.y);
            v0[2] = (short)f2bf(a.z);  v0[3] = (short)f2bf(a.w);
            v0[4] = (short)f2bf(b.x);  v0[5] = (short)f2bf(b.y);
            v0[6] = (short)f2bf(b.z);  v0[7] = (short)f2bf(b.w);
            v1[0] = (short)f2bf(c4.x); v1[1] = (short)f2bf(c4.y);
            v1[2] = (short)f2bf(c4.z); v1[3] = (short)f2bf(c4.w);
            v1[4] = (short)f2bf(d4.x); v1[5] = (short)f2bf(d4.y);
            v1[6] = (short)f2bf(d4.z); v1[7] = (short)f2bf(d4.w);
            int sw = (srow >> 1) & 3;
            int c0 = (scol >> 3) ^ sw;
            int c1 = ((scol >> 3) + 1) ^ sw;
            *(s8x8*)&As[srow * 32 + c0 * 8] = v0;
            *(s8x8*)&As[srow * 32 + c1 * 8] = v1;
        }
        asm volatile("s_waitcnt vmcnt(0)" ::: "memory");
        __syncthreads();

        s8x8 af[4], bf[4];
#pragma unroll
        for (int m = 0; m < 4; m++) {
            int row = wr * 64 + m * 16 + ln15;
            af[m] = *(const s8x8*)&As[row * 32 + (kq ^ ((row >> 1) & 3)) * 8];
        }
#pragma unroll
        for (int n = 0; n < 4; n++) {
            int row = wc * 64 + n * 16 + ln15;
            bf[n] = *(const s8x8*)&Bs[row * 32 + (kq ^ ((row >> 1) & 3)) * 8];
        }
#pragma unroll
        for (int m = 0; m < 4; m++)
#pragma unroll
            for (int n = 0; n < 4; n++)
                acc[m][n] = __builtin_amdgcn_mfma_f32_16x16x32_bf16(
                    af[m], bf[n], acc[m][n], 0, 0, 0);
        __syncthreads();
    }

    const int which = bn >> 3;
    unsigned short* dst = (which == 0) ? t1b : (which == 1) ? qb
                        : (which == 2) ? kb : vb;
    const float scale = (which == 1) ? 0.18033688011112042f : 1.0f;
    const int   relu  = (which == 0);
    const int   cbase = (bn & 7) * 128;

    float bcol[4];
#pragma unroll
    for (int n = 0; n < 4; n++)
        bcol[n] = bcat[bn * 128 + wc * 64 + n * 16 + ln15];
#pragma unroll
    for (int m = 0; m < 4; m++) {
        size_t gr0 = rowA0 + wr * 64 + m * 16 + kq * 4;
#pragma unroll
        for (int n = 0; n < 4; n++) {
            int gc = cbase + wc * 64 + n * 16 + ln15;
#pragma unroll
            for (int j = 0; j < 4; j++) {
                float vv = acc[m][n][j] + bcol[n];
                if (relu) vv = fmaxf(vv, 0.f);
                vv *= scale;
                dst[(gr0 + j) * 1024 + gc] = f2bf(vv);
            }
        }
    }
}

// ---------------------------------------------------------------------------
// Output projection (ROUND-6 EXACT, passing).
// ---------------------------------------------------------------------------
__global__ __launch_bounds__(256) void out_proj(
    const unsigned short* __restrict__ A, const unsigned short* __restrict__ W,
    const float* __restrict__ bias, float* __restrict__ C)
{
    __shared__ __align__(16) short As[64 * 32];
    __shared__ __align__(16) short Bs[128 * 32];
    const int tid  = threadIdx.x;
    const int wave = tid >> 6;
    const int lane = tid & 63;
    const int ln15 = lane & 15;
    const int kq   = lane >> 4;
    const int wr   = wave >> 1;
    const int wc   = wave & 1;
    const size_t rowA0 = (size_t)blockIdx.y * 64;
    const size_t rowB0 = (size_t)blockIdx.x * 128;
    const int lrow   = lane >> 2;
    const int lchunk = lane & 3;

    f32x4 acc[2][4];
#pragma unroll
    for (int m = 0; m < 2; m++)
#pragma unroll
        for (int n = 0; n < 4; n++) acc[m][n] = (f32x4){0.f, 0.f, 0.f, 0.f};

    for (int k0 = 0; k0 < 1024; k0 += 32) {
        {
            int row = wave * 16 + lrow;
            int c   = lchunk ^ ((row >> 1) & 3);
            gload_lds16(A + (rowA0 + row) * 1024 + k0 + c * 8,
                        &As[(wave * 16) * 32]);
        }
#pragma unroll
        for (int i = 0; i < 2; i++) {
            int row = wave * 32 + i * 16 + lrow;
            int c   = lchunk ^ ((row >> 1) & 3);
            gload_lds16(W + (rowB0 + row) * 1024 + k0 + c * 8,
                        &Bs[(wave * 32 + i * 16) * 32]);
        }
        asm volatile("s_waitcnt vmcnt(0)" ::: "memory");
        __syncthreads();

        s8x8 af[2], bf[4];
#pragma unroll
        for (int m = 0; m < 2; m++) {
            int row = wr * 32 + m * 16 + ln15;
            af[m] = *(const s8x8*)&As[row * 32 + (kq ^ ((row >> 1) & 3)) * 8];
        }
#pragma unroll
        for (int n = 0; n < 4; n++) {
            int row = wc * 64 + n * 16 + ln15;
            bf[n] = *(const s8x8*)&Bs[row * 32 + (kq ^ ((row >> 1) & 3)) * 8];
        }
#pragma unroll
        for (int m = 0; m < 2; m++)
#pragma unroll
            for (int n = 0; n < 4; n++)
                acc[m][n] = __builtin_amdgcn_mfma_f32_16x16x32_bf16(
                    af[m], bf[n], acc[m][n], 0, 0, 0);
        __syncthreads();
    }

    float bcol[4];
#pragma unroll
    for (int n = 0; n < 4; n++)
        bcol[n] = bias[rowB0 + wc * 64 + n * 16 + ln15];
#pragma unroll
    for (int m = 0; m < 2; m++) {
        size_t gr0 = rowA0 + wr * 32 + m * 16 + kq * 4;
#pragma unroll
        for (int n = 0; n < 4; n++) {
            size_t gc = rowB0 + wc * 64 + n * 16 + ln15;
#pragma unroll
            for (int j = 0; j < 4; j++)
                C[(gr0 + j) * 1024 + gc] = acc[m][n][j] + bcol[n];
        }
    }
}

// ---------------------------------------------------------------------------
// t2gate body (R11-verbatim).
// ---------------------------------------------------------------------------
__device__ __forceinline__ void t2gate_body(
    int blk, int tid,
    const unsigned short* __restrict__ t1, const unsigned short* __restrict__ W2b,
    const float* __restrict__ b2, const float* __restrict__ hs,
    float* __restrict__ gate,
    short* As, short* Bs, float (*t2s)[65], float (*hss)[65])
{
    const int wave  = tid >> 6;
    const int lane  = tid & 63;
    const int ln15  = lane & 15;
    const int kq    = lane >> 4;
    const int lrow8 = lane >> 3;
    const int lch   = lane & 7;
    const int m0    = blk * 16;

    {
        int r = tid >> 4, c = (tid & 15) * 4;
        float4 v = *(const float4*)(hs + r * 64 + c);
        hss[r][c] = v.x; hss[r][c + 1] = v.y; hss[r][c + 2] = v.z; hss[r][c + 3] = v.w;
    }

    f32x4 acc = (f32x4){0.f, 0.f, 0.f, 0.f};
    for (int k0 = 0; k0 < 1024; k0 += 64) {
        if (wave < 2) {
            int row = wave * 8 + lrow8;
            int cg  = lch ^ (row & 7);
            gload_lds16(t1 + (size_t)(m0 + row) * 1024 + k0 + cg * 8,
                        As + (wave * 8) * 64);
        }
#pragma unroll
        for (int i = 0; i < 2; i++) {
            int row = wave * 16 + i * 8 + lrow8;
            int cg  = lch ^ (row & 7);
            gload_lds16(W2b + (size_t)row * 1024 + k0 + cg * 8,
                        Bs + (wave * 16 + i * 8) * 64);
        }
        asm volatile("s_waitcnt vmcnt(0)" ::: "memory");
        __syncthreads();

#pragma unroll
        for (int kk = 0; kk < 2; kk++) {
            int arow = ln15;
            int brow = wave * 16 + ln15;
            s8x8 af = *(const s8x8*)(As + arow * 64 + (((kk * 4 + kq) ^ (arow & 7)) * 8));
            s8x8 bf = *(const s8x8*)(Bs + brow * 64 + (((kk * 4 + kq) ^ (brow & 7)) * 8));
            acc = __builtin_amdgcn_mfma_f32_16x16x32_bf16(af, bf, acc, 0, 0, 0);
        }
        __syncthreads();
    }

#pragma unroll
    for (int j = 0; j < 4; j++)
        t2s[kq * 4 + j][wave * 16 + ln15] = acc[j] + b2[wave * 16 + ln15];
    __syncthreads();

    int r = tid >> 4, hd = tid & 15;
    float s = 0.f;
#pragma unroll 16
    for (int d = 0; d < 64; d++) s += t2s[r][d] * hss[hd][d];
    float mx = s;
    mx = fmaxf(mx, __shfl_xor(mx, 1));
    mx = fmaxf(mx, __shfl_xor(mx, 2));
    mx = fmaxf(mx, __shfl_xor(mx, 4));
    mx = fmaxf(mx, __shfl_xor(mx, 8));
    float e = __expf(s - mx);
    float sum = e;
    sum += __shfl_xor(sum, 1);
    sum += __shfl_xor(sum, 2);
    sum += __shfl_xor(sum, 4);
    sum += __shfl_xor(sum, 8);
    gate[(size_t)(m0 + r) * Hn + hd] = e / sum;
}

__device__ __forceinline__ void vtrans_body(
    int bh, int t0, int tid,
    const unsigned short* __restrict__ vb, unsigned short* __restrict__ vt,
    unsigned short (*ts)[65])
{
    const int b = bh >> 4, h = bh & 15;
    {
        int tr = tid >> 2, dq = (tid & 3) * 16;
        const unsigned short* src =
            vb + ((size_t)(t0 + tr) * Bn + b) * En + h * 64 + dq;
        s8x8 a = *(const s8x8*)src;
        s8x8 c = *(const s8x8*)(src + 8);
#pragma unroll
        for (int i = 0; i < 8; i++) {
            ts[tr][dq + i]     = (unsigned short)a[i];
            ts[tr][dq + 8 + i] = (unsigned short)c[i];
        }
    }
    __syncthreads();
    {
        int dr = tid >> 2, tq = (tid & 3) * 16;
        unsigned short* dst = vt + ((size_t)bh * 64 + dr) * Tn + t0 + tq;
        s8x8 o0, o1;
#pragma unroll
        for (int i = 0; i < 8; i++) {
            o0[i] = (short)ts[tq + i][dr];
            o1[i] = (short)ts[tq + 8 + i][dr];
        }
        *(s8x8*)dst = o0;
        *(s8x8*)(dst + 8) = o1;
    }
}

// Standalone kernels (!pre path).
__global__ __launch_bounds__(256) void t2gate_k(
    const unsigned short* __restrict__ t1, const unsigned short* __restrict__ W2b,
    const float* __restrict__ b2, const float* __restrict__ hs,
    float* __restrict__ gate)
{
    __shared__ __align__(16) short As[16 * 64];
    __shared__ __align__(16) short Bs[64 * 64];
    __shared__ float t2s[16][65];
    __shared__ float hss[16][65];
    t2gate_body(blockIdx.x, threadIdx.x, t1, W2b, b2, hs, gate, As, Bs, t2s, hss);
}
__global__ __launch_bounds__(256) void trans_wo_k(
    const unsigned short* __restrict__ vb, unsigned short* __restrict__ vt,
    const float* __restrict__ Wo, unsigned short* __restrict__ Wob)
{
    const int bx = blockIdx.x, tid = threadIdx.x;
    if (bx >= 1024) {
        size_t i = (size_t)(bx - 1024) * 256 + tid;
        cast8(Wo + i * 8, Wob + i * 8);
        return;
    }
    __shared__ unsigned short ts[64][65];
    vtrans_body(bx & 63, (bx >> 6) * 64, tid, vb, vt, ts);
}

// Merged mid-stage (pre path, validated R10-R14).
__global__ __launch_bounds__(256) void midstage(
    const unsigned short* __restrict__ t1, const unsigned short* __restrict__ W2b,
    const float* __restrict__ b2, const float* __restrict__ hs,
    float* __restrict__ gate,
    const unsigned short* __restrict__ vb, unsigned short* __restrict__ vt,
    const float* __restrict__ Wo, unsigned short* __restrict__ Wob)
{
    __shared__ __align__(16) short As[16 * 64];
    __shared__ __align__(16) short Bs[64 * 64];
    __shared__ float t2s[16][65];
    __shared__ float hss[16][65];
    __shared__ unsigned short ts[64][65];
    const int bx = blockIdx.x, tid = threadIdx.x;
    if (bx < 256) {
        t2gate_body(bx, tid, t1, W2b, b2, hs, gate, As, Bs, t2s, hss);
    } else if (bx < 1280) {
        int v = bx - 256;
        vtrans_body(v & 63, (v >> 6) * 64, tid, vb, vt, ts);
    } else {
        size_t i = (size_t)(bx - 1280) * 256 + tid;
        cast8(Wo + i * 8, Wob + i * 8);
    }
}

// ---------------------------------------------------------------------------
// MFMA flash attention (R9 8-wave version, passing, unchanged).
// ---------------------------------------------------------------------------
__global__ __launch_bounds__(512, 2) void attn_mfma(
    const unsigned short* __restrict__ q, const unsigned short* __restrict__ k,
    const unsigned short* __restrict__ vt, const float* __restrict__ gate,
    unsigned short* __restrict__ o)
{
    __shared__ __align__(16) short Kls[2][64 * 64];
    __shared__ __align__(16) short Vls[2][64 * 64];

    const int tid  = threadIdx.x;
    const int w    = tid >> 6;
    const int lane = tid & 63;
    const int ln   = lane & 15;
    const int kq   = lane >> 4;
    const int bh   = blockIdx.x;
    const int b    = bh >> 4;
    const int h    = bh & 15;
    const int qt   = blockIdx.y;

    s8x8 qf[2];
    {
        const int qrow = qt * 128 + w * 16 + ln;
        const unsigned short* src =
            q + ((size_t)qrow * Bn + b) * En + h * 64 + kq * 8;
        qf[0] = *(const s8x8*)(src);
        qf[1] = *(const s8x8*)(src + 32);
    }

    f32x4 OT[4];
#pragma unroll
    for (int n = 0; n < 4; n++) OT[n] = (f32x4){0.f, 0.f, 0.f, 0.f};
    float mrun = -1e30f, lrun = 0.f;

    const int srow = w * 8 + (lane >> 3);
    const int sch  = (lane & 7) ^ (srow & 7);
    const int sn  = srow >> 4;
    const int sK0 = 32 * (sn >> 1) + 4 * (sn & 1)
                  + 8 * ((srow >> 2) & 3) + (srow & 3);

    auto stage = [&](int bufi, int s0) {
        const unsigned short* gk =
            k + ((size_t)(s0 + sK0) * Bn + b) * En + h * 64 + sch * 8;
        gload_lds16(gk, &Kls[bufi][w * 512]);
        const unsigned short* gv =
            vt + ((size_t)bh * 64 + srow) * Tn + s0 + sch * 8;
        gload_lds16(gv, &Vls[bufi][w * 512]);
    };

    stage(0, 0);
    asm volatile("s_waitcnt vmcnt(0)" ::: "memory");
    __syncthreads();

    int cur = 0;
    for (int t = 0; t < Tn / 64; t++) {
        if (t + 1 < Tn / 64) stage(cur ^ 1, (t + 1) * 64);

        f32x4 S[4];
        __builtin_amdgcn_s_setprio(1);
#pragma unroll
        for (int n = 0; n < 4; n++) {
            S[n] = (f32x4){0.f, 0.f, 0.f, 0.f};
#pragma unroll
            for (int kk = 0; kk < 2; kk++) {
                int row = n * 16 + ln;
                int cc  = (kk * 4 + kq) ^ (row & 7);
                s8x8 kf = *(const s8x8*)&Kls[cur][row * 64 + cc * 8];
                S[n] = __builtin_amdgcn_mfma_f32_16x16x32_bf16(kf, qf[kk], S[n], 0, 0, 0);
            }
        }
        __builtin_amdgcn_s_setprio(0);

        float rm;
        {
            f32x4 t0 = S[0];
#pragma unroll
            for (int n = 1; n < 4; n++) {
                t0[0] = fmaxf(t0[0], S[n][0]); t0[1] = fmaxf(t0[1], S[n][1]);
                t0[2] = fmaxf(t0[2], S[n][2]); t0[3] = fmaxf(t0[3], S[n][3]);
            }
            rm = fmaxf(fmaxf(t0[0], t0[1]), fmaxf(t0[2], t0[3]));
            rm = fmaxf(rm, __shfl_xor(rm, 16));
            rm = fmaxf(rm, __shfl_xor(rm, 32));
        }

        if (__any(rm > mrun + 8.0f)) {
            float mnew = fmaxf(mrun, rm);
            float fs = exp2asm(mrun - mnew);
            lrun *= fs;
#pragma unroll
            for (int n = 0; n < 4; n++) {
                OT[n][0] *= fs; OT[n][1] *= fs; OT[n][2] *= fs; OT[n][3] *= fs;
            }
            mrun = mnew;
        }

        float ps = 0.f;
#pragma unroll
        for (int n = 0; n < 4; n++) {
            S[n][0] = exp2asm(S[n][0] - mrun); ps += S[n][0];
            S[n][1] = exp2asm(S[n][1] - mrun); ps += S[n][1];
            S[n][2] = exp2asm(S[n][2] - mrun); ps += S[n][2];
            S[n][3] = exp2asm(S[n][3] - mrun); ps += S[n][3];
        }
        ps += __shfl_xor(ps, 16);
        ps += __shfl_xor(ps, 32);
        lrun += ps;

        union { unsigned int u[4]; s8x8 v; } pb[2];
#pragma unroll
        for (int kk = 0; kk < 2; kk++) {
            pb[kk].u[0] = cvtpk(S[2 * kk][0],     S[2 * kk][1]);
            pb[kk].u[1] = cvtpk(S[2 * kk][2],     S[2 * kk][3]);
            pb[kk].u[2] = cvtpk(S[2 * kk + 1][0], S[2 * kk + 1][1]);
            pb[kk].u[3] = cvtpk(S[2 * kk + 1][2], S[2 * kk + 1][3]);
        }

        __builtin_amdgcn_s_setprio(1);
#pragma unroll
        for (int kk = 0; kk < 2; kk++) {
#pragma unroll
            for (int n = 0; n < 4; n++) {
                int row = n * 16 + ln;
                int cv  = (kk * 4 + kq) ^ (row & 7);
                s8x8 vf = *(const s8x8*)&Vls[cur][row * 64 + cv * 8];
                OT[n] = __builtin_amdgcn_mfma_f32_16x16x32_bf16(vf, pb[kk].v, OT[n], 0, 0, 0);
            }
        }
        __builtin_amdgcn_s_setprio(0);

        asm volatile("s_waitcnt vmcnt(0)" ::: "memory");
        __syncthreads();
        cur ^= 1;
    }

    {
        int tq = qt * 128 + w * 16 + ln;
        size_t m = (size_t)tq * Bn + b;
        float g = gate[m * Hn + h] / lrun;
        unsigned short* dst = o + m * En + h * 64;
#pragma unroll
        for (int n = 0; n < 4; n++) {
            int d0 = n * 16 + kq * 4;
            uint2 pkv;
            pkv.x = cvtpk(OT[n][0] * g, OT[n][1] * g);
            pkv.y = cvtpk(OT[n][2] * g, OT[n][3] * g);
            *(uint2*)(dst + d0) = pkv;
        }
    }
}

// ---------------------------------------------------------------------------
// Workspace layout (unchanged from R11-R14).
// pre path (5 dispatches): prep_all, fused_proj8, midstage, attn_mfma,
//   out_proj.  Aliases: vtb <- xb (dead after fused_proj8), Wob <- Wcat
//   (dead after fused_proj8), ob <- vb (dead after V transpose).
// ---------------------------------------------------------------------------
extern "C" void kernel_launch(void* const* d_in, const int* in_sizes, int n_in,
                              void* d_out, int out_size, void* d_ws, size_t ws_size,
                              hipStream_t stream)
{
    const float* x  = (const float*)d_in[0];
    const float* Wq = (const float*)d_in[1];
    const float* bq = (const float*)d_in[2];
    const float* Wk = (const float*)d_in[3];
    const float* bk = (const float*)d_in[4];
    const float* Wv = (const float*)d_in[5];
    const float* bv = (const float*)d_in[6];
    const float* Wo = (const float*)d_in[7];
    const float* bo = (const float*)d_in[8];
    const float* W1 = (const float*)d_in[9];
    const float* b1 = (const float*)d_in[10];
    const float* W2 = (const float*)d_in[11];
    const float* b2 = (const float*)d_in[12];
    const float* hs = (const float*)d_in[13];

    const size_t WELEM = (size_t)En * En;
    unsigned short* Wcat = (unsigned short*)d_ws;            // 4*WELEM
    unsigned short* W2b  = Wcat + 4 * WELEM;                 // 64*1024
    float* bcat = (float*)(W2b + (size_t)SIGn * HIDn);       // 4096 floats
    float* gate = bcat + 4096;                               // 4096*16 floats
    unsigned short* t1b = (unsigned short*)(gate + (size_t)Mn * Hn);
    unsigned short* qb  = t1b + (size_t)Mn * En;
    unsigned short* kb  = qb  + (size_t)Mn * En;
    unsigned short* vb  = kb  + (size_t)Mn * En;
    unsigned short* xb  = vb  + (size_t)Mn * En;             // optional +8MB
    unsigned short* Wob = Wcat;   // alias
    unsigned short* ob  = vb;     // alias

    const size_t need_xb =
        (size_t)((char*)(xb + (size_t)Mn * En) - (char*)d_ws);
    const bool pre = ws_size >= need_xb;   // deterministic

    dim3 blk(256);

    prep_all<<<dim3(512, 9), blk, 0, stream>>>(
        x, W1, Wq, Wk, Wv, W2, b1, bq, bk, bv, Wcat, W2b, bcat, xb, (int)pre);

    if (pre) {
        unsigned short* vtb = xb;    // xb dead after fused_proj8
        fused_proj8<<<dim3(16, 16), dim3(512), 0, stream>>>(
            xb, Wcat, bcat, t1b, qb, kb, vb);
        midstage<<<dim3(1792), blk, 0, stream>>>(
            t1b, W2b, b2, hs, gate, vb, vtb, Wo, Wob);
        attn_mfma<<<dim3(Bn * Hn, Tn / 128), dim3(512), 0, stream>>>(
            qb, kb, vtb, gate, ob);
    } else {
        unsigned short* vtb = t1b;   // t1b dead after t2gate (sequential)
        fused_proj_fb<<<dim3(32, 32), blk, 0, stream>>>(
            x, Wcat, bcat, t1b, qb, kb, vb);
        t2gate_k<<<dim3(Mn / 16), blk, 0, stream>>>(t1b, W2b, b2, hs, gate);
        trans_wo_k<<<dim3(1536), blk, 0, stream>>>(vb, vtb, Wo, Wob);
        attn_mfma<<<dim3(Bn * Hn, Tn / 128), dim3(512), 0, stream>>>(
            qb, kb, vtb, gate, ob);
    }

    out_proj<<<dim3(En / 128, Mn / 64), blk, 0, stream>>>(ob, Wob, bo, (float*)d_out);
}